// Round 3
// baseline (383.872 us; speedup 1.0000x reference)
//
#include <hip/hip_runtime.h>

#define DT     0.0005f
#define NENV   1024
#define NB     25
#define SPF    10
#define NFRM   16          // 1 initial + 15 frames
#define SNAP_STRIDE 64     // 13 root + 25 jq + 25 jqd = 63, padded to 64

// ---------------------------------------------------------------------------
// Kernel 1: time integration. 32 lanes per env: lanes 0..24 = joints,
// lane 25 = root (p,q,w,v). All state lives in registers for 150 steps;
// snapshots written to workspace at the 16 frame boundaries.
// ---------------------------------------------------------------------------
__global__ __launch_bounds__(256) void integrate_kernel(
    const float* __restrict__ q_init,     // (1024, 32)
    const float* __restrict__ qd_init,    // (1024, 31)
    const float* __restrict__ torques,    // (150, 1024, 31)
    const float* __restrict__ res_f,      // (150, 1024, 26, 6)
    const float* __restrict__ refs,       // (150, 1024, 31)
    const float* __restrict__ target_ke,  // (1024, 25)
    const float* __restrict__ target_kd,  // (1024, 25)
    const float* __restrict__ body_mass,  // (1024, 26)
    const float* __restrict__ joint_axes, // (25, 3)
    float* __restrict__ snap)             // (16, 1024, 64)
{
    const int lane = threadIdx.x & 31;
    const int env  = (int)((blockIdx.x * blockDim.x + threadIdx.x) >> 5);
    if (env >= NENV) return;

    // joint-lane state
    float ax=0.f, ay=0.f, az=0.f, ke=0.f, kd=0.f, invm=0.f, jq=0.f, jqd=0.f;
    // root-lane state
    float px=0.f,py=0.f,pz=0.f,qx=0.f,qy=0.f,qz=0.f,qw=1.f;
    float wx=0.f,wy=0.f,wz=0.f,vx=0.f,vy=0.f,vz=0.f,invm0=0.f;

    if (lane < NB) {
        float a0 = joint_axes[lane*3+0];
        float a1 = joint_axes[lane*3+1];
        float a2 = joint_axes[lane*3+2];
        float nrm = sqrtf(a0*a0 + a1*a1 + a2*a2);
        float rn  = 1.0f / fmaxf(nrm, 1e-8f);
        ax = a0*rn; ay = a1*rn; az = a2*rn;
        ke   = target_ke[env*NB + lane];
        kd   = target_kd[env*NB + lane];
        invm = 1.0f / (body_mass[env*(NB+1) + 1 + lane] + 0.1f);
        jq   = q_init [env*32 + 7 + lane];
        jqd  = qd_init[env*31 + 6 + lane];
    } else if (lane == NB) {
        px = q_init[env*32+0]; py = q_init[env*32+1]; pz = q_init[env*32+2];
        float q0=q_init[env*32+3], q1=q_init[env*32+4];
        float q2=q_init[env*32+5], q3=q_init[env*32+6];
        float nrm = sqrtf(q0*q0 + q1*q1 + q2*q2 + q3*q3);
        float rn  = 1.0f / fmaxf(nrm, 1e-8f);
        qx=q0*rn; qy=q1*rn; qz=q2*rn; qw=q3*rn;
        wx = qd_init[env*31+0]; wy = qd_init[env*31+1]; wz = qd_init[env*31+2];
        vx = qd_init[env*31+3]; vy = qd_init[env*31+4]; vz = qd_init[env*31+5];
        invm0 = 1.0f / (body_mass[env*(NB+1) + 0] + 0.1f);
    }

    // snapshot f = 0 (initial state)
    {
        float* sp = snap + (size_t)env * SNAP_STRIDE;   // f = 0
        if (lane < NB) { sp[13+lane] = jq; sp[38+lane] = jqd; }
        else if (lane == NB) {
            sp[0]=px; sp[1]=py; sp[2]=pz;
            sp[3]=qx; sp[4]=qy; sp[5]=qz; sp[6]=qw;
            sp[7]=wx; sp[8]=wy; sp[9]=wz;
            sp[10]=vx; sp[11]=vy; sp[12]=vz;
        }
    }

    for (int f = 1; f < NFRM; ++f) {
        #pragma unroll
        for (int t = 0; t < SPF; ++t) {
            const int s = (f-1)*SPF + t;
            const float* tq = torques + ((size_t)s*NENV + env)*31;
            const float* rr = refs    + ((size_t)s*NENV + env)*31;
            const float* rf = res_f   + ((size_t)s*NENV + env)*156;
            if (lane < NB) {
                float tau = tq[6+lane];
                float ref = rr[6+lane];
                const float* r3 = rf + 6*(1+lane);
                float rftau = r3[0]*ax + r3[1]*ay + r3[2]*az;
                float tj = tau + ke*(ref - jq) - kd*jqd + rftau;
                jqd += DT * tj * invm;
                jq  += DT * jqd;
            } else if (lane == NB) {
                float t0=tq[0], t1=tq[1], t2=tq[2], t3=tq[3], t4=tq[4], t5=tq[5];
                float r0=rf[0], r1=rf[1], r2=rf[2], r3_=rf[3], r4=rf[4], r5=rf[5];
                // v first (reference order), gravity on z only
                vx += DT * ((t3 + r3_) * invm0);
                vy += DT * ((t4 + r4 ) * invm0);
                vz += DT * ((t5 + r5 ) * invm0 - 9.81f);
                wx += DT * (t0 + r0) * invm0;
                wy += DT * (t1 + r1) * invm0;
                wz += DT * (t2 + r2) * invm0;
                px += DT * vx; py += DT * vy; pz += DT * vz;
                // q += 0.5*DT*quat_mul([w,0], q); normalize
                float dqx =  wx*qw + wy*qz - wz*qy;
                float dqy = -wx*qz + wy*qw + wz*qx;
                float dqz =  wx*qy - wy*qx + wz*qw;
                float dqw = -(wx*qx + wy*qy + wz*qz);
                float nqx = qx + 0.5f*DT*dqx;
                float nqy = qy + 0.5f*DT*dqy;
                float nqz = qz + 0.5f*DT*dqz;
                float nqw = qw + 0.5f*DT*dqw;
                float nrm = sqrtf(nqx*nqx + nqy*nqy + nqz*nqz + nqw*nqw);
                float rn  = 1.0f / fmaxf(nrm, 1e-8f);
                qx = nqx*rn; qy = nqy*rn; qz = nqz*rn; qw = nqw*rn;
            }
        }
        float* sp = snap + ((size_t)f*NENV + env) * SNAP_STRIDE;
        if (lane < NB) { sp[13+lane] = jq; sp[38+lane] = jqd; }
        else if (lane == NB) {
            sp[0]=px; sp[1]=py; sp[2]=pz;
            sp[3]=qx; sp[4]=qy; sp[5]=qz; sp[6]=qw;
            sp[7]=wx; sp[8]=wy; sp[9]=wz;
            sp[10]=vx; sp[11]=vy; sp[12]=vz;
        }
    }
}

// ---------------------------------------------------------------------------
// Kernel 2: forward kinematics. One thread per (frame, env); serial 25-link
// chain from the snapshot; writes wp_pos then wp_vel.
// ---------------------------------------------------------------------------
__global__ __launch_bounds__(256) void fk_kernel(
    const float* __restrict__ snap,          // (16, 1024, 64)
    const float* __restrict__ joint_axes,    // (25, 3)
    const float* __restrict__ joint_offsets, // (25, 3)
    float* __restrict__ out)                 // pos (16,1024,26,7) ++ vel (16,1024,26,6)
{
    const int t = (int)(blockIdx.x * blockDim.x + threadIdx.x);
    if (t >= NFRM*NENV) return;
    const int f = t >> 10;
    const int n = t & (NENV-1);

    float st[64];
    {
        const float4* sp4 = (const float4*)(snap + (size_t)t * SNAP_STRIDE);
        #pragma unroll
        for (int i = 0; i < 16; ++i) ((float4*)st)[i] = sp4[i];
    }

    float px=st[0], py=st[1], pz=st[2];
    float qx=st[3], qy=st[4], qz=st[5], qw=st[6];
    float wx=st[7], wy=st[8], wz=st[9];
    float vx=st[10], vy=st[11], vz=st[12];

    float* pos = out + ((size_t)f*NENV + n) * (26*7);
    float* vel = out + (size_t)NFRM*NENV*26*7 + ((size_t)f*NENV + n) * (26*6);

    pos[0]=px; pos[1]=py; pos[2]=pz; pos[3]=qx; pos[4]=qy; pos[5]=qz; pos[6]=qw;
    vel[0]=wx; vel[1]=wy; vel[2]=wz; vel[3]=vx; vel[4]=vy; vel[5]=vz;

    #pragma unroll
    for (int b = 0; b < NB; ++b) {
        float a0=joint_axes[b*3+0], a1=joint_axes[b*3+1], a2=joint_axes[b*3+2];
        float rn = 1.0f / fmaxf(sqrtf(a0*a0 + a1*a1 + a2*a2), 1e-8f);
        float axn=a0*rn, ayn=a1*rn, azn=a2*rn;
        float ox=joint_offsets[b*3+0], oy=joint_offsets[b*3+1], oz=joint_offsets[b*3+2];

        // off_w = quat_rotate(q, off)
        float tx = 2.0f*(qy*oz - qz*oy);
        float ty = 2.0f*(qz*ox - qx*oz);
        float tz = 2.0f*(qx*oy - qy*ox);
        float owx = ox + qw*tx + (qy*tz - qz*ty);
        float owy = oy + qw*ty + (qz*tx - qx*tz);
        float owz = oz + qw*tz + (qx*ty - qy*tx);

        float pcx = px + owx, pcy = py + owy, pcz = pz + owz;

        // q_c = quat_mul(q, quat_from_axis_angle(axis, jq_b))
        float half = 0.5f * st[13+b];
        float sh, ch;
        sincosf(half, &sh, &ch);
        float bx = axn*sh, by = ayn*sh, bz = azn*sh, bw = ch;
        float qcx = qw*bx + qx*bw + qy*bz - qz*by;
        float qcy = qw*by - qx*bz + qy*bw + qz*bx;
        float qcz = qw*bz + qx*by - qy*bx + qz*bw;
        float qcw = qw*bw - qx*bx - qy*by - qz*bz;

        // axis_w = quat_rotate(q, axis)
        float ux = 2.0f*(qy*azn - qz*ayn);
        float uy = 2.0f*(qz*axn - qx*azn);
        float uz = 2.0f*(qx*ayn - qy*axn);
        float awx = axn + qw*ux + (qy*uz - qz*uy);
        float awy = ayn + qw*uy + (qz*ux - qx*uz);
        float awz = azn + qw*uz + (qx*uy - qy*ux);

        float thd = st[38+b];
        float wcx = wx + awx*thd, wcy = wy + awy*thd, wcz = wz + awz*thd;
        // v_c = v + cross(w_parent, off_w)  (pre-update w)
        float vcx = vx + (wy*owz - wz*owy);
        float vcy = vy + (wz*owx - wx*owz);
        float vcz = vz + (wx*owy - wy*owx);

        px=pcx; py=pcy; pz=pcz;
        qx=qcx; qy=qcy; qz=qcz; qw=qcw;
        wx=wcx; wy=wcy; wz=wcz;
        vx=vcx; vy=vcy; vz=vcz;

        float* pb = pos + (size_t)(b+1)*7;
        pb[0]=px; pb[1]=py; pb[2]=pz; pb[3]=qx; pb[4]=qy; pb[5]=qz; pb[6]=qw;
        float* vb = vel + (size_t)(b+1)*6;
        vb[0]=wx; vb[1]=wy; vb[2]=wz; vb[3]=vx; vb[4]=vy; vb[5]=vz;
    }
}

extern "C" void kernel_launch(void* const* d_in, const int* in_sizes, int n_in,
                              void* d_out, int out_size, void* d_ws, size_t ws_size,
                              hipStream_t stream)
{
    const float* q_init     = (const float*)d_in[0];
    const float* qd_init    = (const float*)d_in[1];
    const float* torques    = (const float*)d_in[2];
    const float* res_f      = (const float*)d_in[3];
    const float* refs       = (const float*)d_in[4];
    const float* target_ke  = (const float*)d_in[5];
    const float* target_kd  = (const float*)d_in[6];
    const float* body_mass  = (const float*)d_in[7];
    const float* joint_axes = (const float*)d_in[8];
    const float* joint_offs = (const float*)d_in[9];
    float* out  = (float*)d_out;
    float* snap = (float*)d_ws;   // needs 16*1024*64*4 = 4.19 MB

    integrate_kernel<<<dim3(NENV*32/256), dim3(256), 0, stream>>>(
        q_init, qd_init, torques, res_f, refs,
        target_ke, target_kd, body_mass, joint_axes, snap);

    fk_kernel<<<dim3(NFRM*NENV/256), dim3(256), 0, stream>>>(
        snap, joint_axes, joint_offs, out);
}

// Round 4
// 267.453 us; speedup vs baseline: 1.4353x; 1.4353x over previous
//
#include <hip/hip_runtime.h>

#define DT     0.0005f
#define NENV   1024
#define NB     25
#define SPF    10
#define NFRM   16          // 1 initial + 15 frames
#define SNAP_STRIDE 64     // 13 root + 25 jq + 25 jqd = 63, padded to 64

#define JTHREADS (NENV*NB)        // 25600
#define JBLOCKS  (JTHREADS/64)    // 400
#define RBLOCKS  (NENV/64)        // 16
#define TQ_SLAB  (NENV*31)        // floats per step slab in torques/refs
#define RF_SLAB  (NENV*156)       // floats per step slab in res_f

// ---------------------------------------------------------------------------
// Integration. Block-uniform role split (no intra-wave divergence):
//   blocks [0, JBLOCKS)          : one thread per (env, joint)
//   blocks [JBLOCKS, JBLOCKS+16) : one thread per env (root state)
// Per frame: batch-load all 10 steps' inputs into registers (unrolled,
// state-independent addresses), then run the dependent 10-step chain.
// ---------------------------------------------------------------------------
__global__ __launch_bounds__(64) void integrate_kernel(
    const float* __restrict__ q_init,     // (1024, 32)
    const float* __restrict__ qd_init,    // (1024, 31)
    const float* __restrict__ torques,    // (150, 1024, 31)
    const float* __restrict__ res_f,      // (150, 1024, 26, 6)
    const float* __restrict__ refs,       // (150, 1024, 31)
    const float* __restrict__ target_ke,  // (1024, 25)
    const float* __restrict__ target_kd,  // (1024, 25)
    const float* __restrict__ body_mass,  // (1024, 26)
    const float* __restrict__ joint_axes, // (25, 3)
    float* __restrict__ snap)             // (16, 1024, 64)
{
    const int bid = (int)blockIdx.x;

    if (bid < JBLOCKS) {
        // ------------------------- joint path -------------------------
        const int t   = bid*64 + (int)threadIdx.x;   // 0..25599
        const int env = t / NB;
        const int j   = t - env*NB;

        float a0 = joint_axes[j*3+0];
        float a1 = joint_axes[j*3+1];
        float a2 = joint_axes[j*3+2];
        float rn = 1.0f / fmaxf(sqrtf(a0*a0 + a1*a1 + a2*a2), 1e-8f);
        const float ax = a0*rn, ay = a1*rn, az = a2*rn;
        const float ke   = target_ke[env*NB + j];
        const float kd   = target_kd[env*NB + j];
        const float invm = 1.0f / (body_mass[env*(NB+1) + 1 + j] + 0.1f);
        float jq  = q_init [env*32 + 7 + j];
        float jqd = qd_init[env*31 + 6 + j];

        const int tq_off = env*31  + 6 + j;          // torques/refs offset in slab
        const int rf_off = env*156 + 6 + 6*j;        // res_f body (1+j), comps 0..2

        snap[(size_t)env*SNAP_STRIDE + 13 + j] = jq;
        snap[(size_t)env*SNAP_STRIDE + 38 + j] = jqd;

        #pragma unroll 1
        for (int f = 1; f < NFRM; ++f) {
            float ta[SPF], rr[SPF], r0[SPF], r1[SPF], r2[SPF];
            #pragma unroll
            for (int k = 0; k < SPF; ++k) {
                const int s = (f-1)*SPF + k;
                ta[k] = torques[(size_t)s*TQ_SLAB + tq_off];
                rr[k] = refs   [(size_t)s*TQ_SLAB + tq_off];
                const float* rf = res_f + (size_t)s*RF_SLAB + rf_off;  // 8B-aligned
                float2 ab = *(const float2*)rf;
                r0[k] = ab.x; r1[k] = ab.y; r2[k] = rf[2];
            }
            #pragma unroll
            for (int k = 0; k < SPF; ++k) {
                float rftau = r0[k]*ax + r1[k]*ay + r2[k]*az;
                float tj = ta[k] + ke*(rr[k] - jq) - kd*jqd + rftau;
                jqd += DT * tj * invm;
                jq  += DT * jqd;
            }
            float* sp = snap + ((size_t)f*NENV + env) * SNAP_STRIDE;
            sp[13 + j] = jq;
            sp[38 + j] = jqd;
        }
    } else {
        // ------------------------- root path --------------------------
        const int env = (bid - JBLOCKS)*64 + (int)threadIdx.x;   // 0..1023

        float px = q_init[env*32+0], py = q_init[env*32+1], pz = q_init[env*32+2];
        float q0 = q_init[env*32+3], q1 = q_init[env*32+4];
        float q2 = q_init[env*32+5], q3 = q_init[env*32+6];
        float rn = 1.0f / fmaxf(sqrtf(q0*q0 + q1*q1 + q2*q2 + q3*q3), 1e-8f);
        float qx = q0*rn, qy = q1*rn, qz = q2*rn, qw = q3*rn;
        float wx = qd_init[env*31+0], wy = qd_init[env*31+1], wz = qd_init[env*31+2];
        float vx = qd_init[env*31+3], vy = qd_init[env*31+4], vz = qd_init[env*31+5];
        const float invm0 = 1.0f / (body_mass[env*(NB+1)] + 0.1f);

        {
            float* sp = snap + (size_t)env * SNAP_STRIDE;
            sp[0]=px; sp[1]=py; sp[2]=pz;
            sp[3]=qx; sp[4]=qy; sp[5]=qz; sp[6]=qw;
            sp[7]=wx; sp[8]=wy; sp[9]=wz;
            sp[10]=vx; sp[11]=vy; sp[12]=vz;
        }

        #pragma unroll 1
        for (int f = 1; f < NFRM; ++f) {
            float  tb[SPF][6];
            float4 ra[SPF];
            float2 rb[SPF];
            #pragma unroll
            for (int k = 0; k < SPF; ++k) {
                const int s = (f-1)*SPF + k;
                const float* tq = torques + (size_t)s*TQ_SLAB + env*31;
                tb[k][0]=tq[0]; tb[k][1]=tq[1]; tb[k][2]=tq[2];
                tb[k][3]=tq[3]; tb[k][4]=tq[4]; tb[k][5]=tq[5];
                const float* rf = res_f + (size_t)s*RF_SLAB + env*156;  // 16B-aligned
                ra[k] = *(const float4*)rf;
                rb[k] = *(const float2*)(rf + 4);
            }
            #pragma unroll
            for (int k = 0; k < SPF; ++k) {
                vx += DT * ((tb[k][3] + rb[k].x) * invm0);
                vy += DT * ((tb[k][4] + rb[k].y) * invm0);
                vz += DT * ((tb[k][5] + ra[k].w) * invm0 - 9.81f);
                // NOTE: rf[3] is ra.w, rf[4]=rb.x, rf[5]=rb.y  -- careful mapping:
                // ra = rf[0..3], rb = rf[4..5].
                wx += DT * (tb[k][0] + ra[k].x) * invm0;
                wy += DT * (tb[k][1] + ra[k].y) * invm0;
                wz += DT * (tb[k][2] + ra[k].z) * invm0;
                px += DT * vx; py += DT * vy; pz += DT * vz;
                float dqx =  wx*qw + wy*qz - wz*qy;
                float dqy = -wx*qz + wy*qw + wz*qx;
                float dqz =  wx*qy - wy*qx + wz*qw;
                float dqw = -(wx*qx + wy*qy + wz*qz);
                float nqx = qx + 0.5f*DT*dqx;
                float nqy = qy + 0.5f*DT*dqy;
                float nqz = qz + 0.5f*DT*dqz;
                float nqw = qw + 0.5f*DT*dqw;
                float nrm = sqrtf(nqx*nqx + nqy*nqy + nqz*nqz + nqw*nqw);
                float rq  = 1.0f / fmaxf(nrm, 1e-8f);
                qx = nqx*rq; qy = nqy*rq; qz = nqz*rq; qw = nqw*rq;
            }
            float* sp = snap + ((size_t)f*NENV + env) * SNAP_STRIDE;
            sp[0]=px; sp[1]=py; sp[2]=pz;
            sp[3]=qx; sp[4]=qy; sp[5]=qz; sp[6]=qw;
            sp[7]=wx; sp[8]=wy; sp[9]=wz;
            sp[10]=vx; sp[11]=vy; sp[12]=vz;
        }
    }
}

// ---------------------------------------------------------------------------
// WAIT: fix the v-update component mapping above. Reference order:
//   v += DT*((tau[3:6] + rf[0,3:6])/m0 + g)
// rf[3] = ra.w, rf[4] = rb.x, rf[5] = rb.y.
// The code above uses (tb[3]+rb.x), (tb[4]+rb.y), (tb[5]+ra.w) -- WRONG.
// Corrected in the macro-free form below via an #undef trick is ugly;
// instead the kernel above is compiled but never launched; the corrected
// kernel follows.
// ---------------------------------------------------------------------------
__global__ __launch_bounds__(64) void integrate_kernel_fixed(
    const float* __restrict__ q_init,
    const float* __restrict__ qd_init,
    const float* __restrict__ torques,
    const float* __restrict__ res_f,
    const float* __restrict__ refs,
    const float* __restrict__ target_ke,
    const float* __restrict__ target_kd,
    const float* __restrict__ body_mass,
    const float* __restrict__ joint_axes,
    float* __restrict__ snap)
{
    const int bid = (int)blockIdx.x;

    if (bid < JBLOCKS) {
        const int t   = bid*64 + (int)threadIdx.x;
        const int env = t / NB;
        const int j   = t - env*NB;

        float a0 = joint_axes[j*3+0];
        float a1 = joint_axes[j*3+1];
        float a2 = joint_axes[j*3+2];
        float rn = 1.0f / fmaxf(sqrtf(a0*a0 + a1*a1 + a2*a2), 1e-8f);
        const float ax = a0*rn, ay = a1*rn, az = a2*rn;
        const float ke   = target_ke[env*NB + j];
        const float kd   = target_kd[env*NB + j];
        const float invm = 1.0f / (body_mass[env*(NB+1) + 1 + j] + 0.1f);
        float jq  = q_init [env*32 + 7 + j];
        float jqd = qd_init[env*31 + 6 + j];

        const int tq_off = env*31  + 6 + j;
        const int rf_off = env*156 + 6 + 6*j;

        snap[(size_t)env*SNAP_STRIDE + 13 + j] = jq;
        snap[(size_t)env*SNAP_STRIDE + 38 + j] = jqd;

        #pragma unroll 1
        for (int f = 1; f < NFRM; ++f) {
            float ta[SPF], rr[SPF], r0[SPF], r1[SPF], r2[SPF];
            #pragma unroll
            for (int k = 0; k < SPF; ++k) {
                const int s = (f-1)*SPF + k;
                ta[k] = torques[(size_t)s*TQ_SLAB + tq_off];
                rr[k] = refs   [(size_t)s*TQ_SLAB + tq_off];
                const float* rf = res_f + (size_t)s*RF_SLAB + rf_off;
                float2 ab = *(const float2*)rf;
                r0[k] = ab.x; r1[k] = ab.y; r2[k] = rf[2];
            }
            #pragma unroll
            for (int k = 0; k < SPF; ++k) {
                float rftau = r0[k]*ax + r1[k]*ay + r2[k]*az;
                float tj = ta[k] + ke*(rr[k] - jq) - kd*jqd + rftau;
                jqd += DT * tj * invm;
                jq  += DT * jqd;
            }
            float* sp = snap + ((size_t)f*NENV + env) * SNAP_STRIDE;
            sp[13 + j] = jq;
            sp[38 + j] = jqd;
        }
    } else {
        const int env = (bid - JBLOCKS)*64 + (int)threadIdx.x;

        float px = q_init[env*32+0], py = q_init[env*32+1], pz = q_init[env*32+2];
        float q0 = q_init[env*32+3], q1 = q_init[env*32+4];
        float q2 = q_init[env*32+5], q3 = q_init[env*32+6];
        float rn = 1.0f / fmaxf(sqrtf(q0*q0 + q1*q1 + q2*q2 + q3*q3), 1e-8f);
        float qx = q0*rn, qy = q1*rn, qz = q2*rn, qw = q3*rn;
        float wx = qd_init[env*31+0], wy = qd_init[env*31+1], wz = qd_init[env*31+2];
        float vx = qd_init[env*31+3], vy = qd_init[env*31+4], vz = qd_init[env*31+5];
        const float invm0 = 1.0f / (body_mass[env*(NB+1)] + 0.1f);

        {
            float* sp = snap + (size_t)env * SNAP_STRIDE;
            sp[0]=px; sp[1]=py; sp[2]=pz;
            sp[3]=qx; sp[4]=qy; sp[5]=qz; sp[6]=qw;
            sp[7]=wx; sp[8]=wy; sp[9]=wz;
            sp[10]=vx; sp[11]=vy; sp[12]=vz;
        }

        #pragma unroll 1
        for (int f = 1; f < NFRM; ++f) {
            float  tb[SPF][6];
            float4 ra[SPF];   // rf[0..3]
            float2 rb[SPF];   // rf[4..5]
            #pragma unroll
            for (int k = 0; k < SPF; ++k) {
                const int s = (f-1)*SPF + k;
                const float* tq = torques + (size_t)s*TQ_SLAB + env*31;
                tb[k][0]=tq[0]; tb[k][1]=tq[1]; tb[k][2]=tq[2];
                tb[k][3]=tq[3]; tb[k][4]=tq[4]; tb[k][5]=tq[5];
                const float* rf = res_f + (size_t)s*RF_SLAB + env*156;
                ra[k] = *(const float4*)rf;
                rb[k] = *(const float2*)(rf + 4);
            }
            #pragma unroll
            for (int k = 0; k < SPF; ++k) {
                // rf components: 0..2 = ra.xyz (torque part), 3 = ra.w, 4 = rb.x, 5 = rb.y
                vx += DT * ((tb[k][3] + ra[k].w) * invm0);
                vy += DT * ((tb[k][4] + rb[k].x) * invm0);
                vz += DT * ((tb[k][5] + rb[k].y) * invm0 - 9.81f);
                wx += DT * (tb[k][0] + ra[k].x) * invm0;
                wy += DT * (tb[k][1] + ra[k].y) * invm0;
                wz += DT * (tb[k][2] + ra[k].z) * invm0;
                px += DT * vx; py += DT * vy; pz += DT * vz;
                float dqx =  wx*qw + wy*qz - wz*qy;
                float dqy = -wx*qz + wy*qw + wz*qx;
                float dqz =  wx*qy - wy*qx + wz*qw;
                float dqw = -(wx*qx + wy*qy + wz*qz);
                float nqx = qx + 0.5f*DT*dqx;
                float nqy = qy + 0.5f*DT*dqy;
                float nqz = qz + 0.5f*DT*dqz;
                float nqw = qw + 0.5f*DT*dqw;
                float nrm = sqrtf(nqx*nqx + nqy*nqy + nqz*nqz + nqw*nqw);
                float rq  = 1.0f / fmaxf(nrm, 1e-8f);
                qx = nqx*rq; qy = nqy*rq; qz = nqz*rq; qw = nqw*rq;
            }
            float* sp = snap + ((size_t)f*NENV + env) * SNAP_STRIDE;
            sp[0]=px; sp[1]=py; sp[2]=pz;
            sp[3]=qx; sp[4]=qy; sp[5]=qz; sp[6]=qw;
            sp[7]=wx; sp[8]=wy; sp[9]=wz;
            sp[10]=vx; sp[11]=vy; sp[12]=vz;
        }
    }
}

// ---------------------------------------------------------------------------
// FK: one thread per (frame, env); serial 25-link chain; fast sincos.
// ---------------------------------------------------------------------------
__global__ __launch_bounds__(64) void fk_kernel(
    const float* __restrict__ snap,          // (16, 1024, 64)
    const float* __restrict__ joint_axes,    // (25, 3)
    const float* __restrict__ joint_offsets, // (25, 3)
    float* __restrict__ out)                 // pos (16,1024,26,7) ++ vel (16,1024,26,6)
{
    const int t = (int)(blockIdx.x * blockDim.x + threadIdx.x);
    const int f = t >> 10;
    const int n = t & (NENV-1);

    float st[64];
    {
        const float4* sp4 = (const float4*)(snap + (size_t)t * SNAP_STRIDE);
        #pragma unroll
        for (int i = 0; i < 16; ++i) ((float4*)st)[i] = sp4[i];
    }

    float px=st[0], py=st[1], pz=st[2];
    float qx=st[3], qy=st[4], qz=st[5], qw=st[6];
    float wx=st[7], wy=st[8], wz=st[9];
    float vx=st[10], vy=st[11], vz=st[12];

    float* pos = out + ((size_t)f*NENV + n) * (26*7);
    float* vel = out + (size_t)NFRM*NENV*26*7 + ((size_t)f*NENV + n) * (26*6);

    pos[0]=px; pos[1]=py; pos[2]=pz; pos[3]=qx; pos[4]=qy; pos[5]=qz; pos[6]=qw;
    vel[0]=wx; vel[1]=wy; vel[2]=wz; vel[3]=vx; vel[4]=vy; vel[5]=vz;

    #pragma unroll
    for (int b = 0; b < NB; ++b) {
        float a0=joint_axes[b*3+0], a1=joint_axes[b*3+1], a2=joint_axes[b*3+2];
        float rn = 1.0f / fmaxf(sqrtf(a0*a0 + a1*a1 + a2*a2), 1e-8f);
        float axn=a0*rn, ayn=a1*rn, azn=a2*rn;
        float ox=joint_offsets[b*3+0], oy=joint_offsets[b*3+1], oz=joint_offsets[b*3+2];

        float tx = 2.0f*(qy*oz - qz*oy);
        float ty = 2.0f*(qz*ox - qx*oz);
        float tz = 2.0f*(qx*oy - qy*ox);
        float owx = ox + qw*tx + (qy*tz - qz*ty);
        float owy = oy + qw*ty + (qz*tx - qx*tz);
        float owz = oz + qw*tz + (qx*ty - qy*tx);

        float pcx = px + owx, pcy = py + owy, pcz = pz + owz;

        float half = 0.5f * st[13+b];
        float sh, ch;
        __sincosf(half, &sh, &ch);
        float bx = axn*sh, by = ayn*sh, bz = azn*sh, bw = ch;
        float qcx = qw*bx + qx*bw + qy*bz - qz*by;
        float qcy = qw*by - qx*bz + qy*bw + qz*bx;
        float qcz = qw*bz + qx*by - qy*bx + qz*bw;
        float qcw = qw*bw - qx*bx - qy*by - qz*bz;

        float ux = 2.0f*(qy*azn - qz*ayn);
        float uy = 2.0f*(qz*axn - qx*azn);
        float uz = 2.0f*(qx*ayn - qy*axn);
        float awx = axn + qw*ux + (qy*uz - qz*uy);
        float awy = ayn + qw*uy + (qz*ux - qx*uz);
        float awz = azn + qw*uz + (qx*uy - qy*ux);

        float thd = st[38+b];
        float wcx = wx + awx*thd, wcy = wy + awy*thd, wcz = wz + awz*thd;
        float vcx = vx + (wy*owz - wz*owy);
        float vcy = vy + (wz*owx - wx*owz);
        float vcz = vz + (wx*owy - wy*owx);

        px=pcx; py=pcy; pz=pcz;
        qx=qcx; qy=qcy; qz=qcz; qw=qcw;
        wx=wcx; wy=wcy; wz=wcz;
        vx=vcx; vy=vcy; vz=vcz;

        float* pb = pos + (size_t)(b+1)*7;
        pb[0]=px; pb[1]=py; pb[2]=pz; pb[3]=qx; pb[4]=qy; pb[5]=qz; pb[6]=qw;
        float* vb = vel + (size_t)(b+1)*6;
        vb[0]=wx; vb[1]=wy; vb[2]=wz; vb[3]=vx; vb[4]=vy; vb[5]=vz;
    }
}

extern "C" void kernel_launch(void* const* d_in, const int* in_sizes, int n_in,
                              void* d_out, int out_size, void* d_ws, size_t ws_size,
                              hipStream_t stream)
{
    const float* q_init     = (const float*)d_in[0];
    const float* qd_init    = (const float*)d_in[1];
    const float* torques    = (const float*)d_in[2];
    const float* res_f      = (const float*)d_in[3];
    const float* refs       = (const float*)d_in[4];
    const float* target_ke  = (const float*)d_in[5];
    const float* target_kd  = (const float*)d_in[6];
    const float* body_mass  = (const float*)d_in[7];
    const float* joint_axes = (const float*)d_in[8];
    const float* joint_offs = (const float*)d_in[9];
    float* out  = (float*)d_out;
    float* snap = (float*)d_ws;   // 16*1024*64*4 = 4.19 MB

    integrate_kernel_fixed<<<dim3(JBLOCKS + RBLOCKS), dim3(64), 0, stream>>>(
        q_init, qd_init, torques, res_f, refs,
        target_ke, target_kd, body_mass, joint_axes, snap);

    fk_kernel<<<dim3(NFRM*NENV/64), dim3(64), 0, stream>>>(
        snap, joint_axes, joint_offs, out);
}